// Round 1
// baseline (317.105 us; speedup 1.0000x reference)
//
#include <hip/hip_runtime.h>
#include <stdint.h>

// Problem constants (B, DIM, H, W) = (8, 256, 64, 64), HEADS=4
#define BATCH 8
#define DIM   256
#define NTOK  4096   // H*W
#define NH    4

using bf16x8  = __attribute__((ext_vector_type(8))) __bf16;
using short4v = __attribute__((ext_vector_type(4))) short;
using f32x4   = __attribute__((ext_vector_type(4))) float;

__device__ __forceinline__ short f2bf(float f) {
  union { float f; uint32_t u; } v; v.f = f;
  uint32_t r = v.u + 0x7fffu + ((v.u >> 16) & 1u);   // RNE
  return (short)(r >> 16);
}

// ---------------- shared GEMM core ----------------
// C[128][128] (f32 acc) = A[128 x K] * B[128 x K]^T, both operands K-major bf16.
// 256 threads = 4 waves in 2x2, each wave owns a 64x64 quadrant (4x4 frags of 16x16).
// mfma_f32_16x16x32_bf16: A-frag lane l holds A[l&15][(l>>4)*8 + j] (8 contig K);
// C/D: row=(l>>4)*4+r, col=l&15  [learn_hip m89-verified].
#define BK 32

__device__ __forceinline__ void stage_tile(const short* g, short* lds, int ld, int tid) {
  // 128 rows x 32 cols bf16 (8 KB) via global_load_lds width=16.
  // LDS dest must be wave-uniform base; HW writes lane l at base + l*16.
  const int wave = tid >> 6, lane = tid & 63;
#pragma unroll
  for (int r = 0; r < 2; ++r) {
    const int chunk = wave * 2 + r;                       // 0..7, 16 rows each
    const short* src = g + (size_t)(chunk * 16 + (lane >> 2)) * ld + (lane & 3) * 8;
    __builtin_amdgcn_global_load_lds(
        (const __attribute__((address_space(1))) void*)src,
        (__attribute__((address_space(3))) void*)(lds + chunk * 512),
        16, 0, 0);
  }
}

__device__ __forceinline__ void gemm_core(const short* Ag, const short* Bg, int K,
                                          f32x4 acc[4][4], short* As, short* Bs) {
  const int tid  = threadIdx.x;
  const int lane = tid & 63;
  const int wave = tid >> 6;
  const int wm = (wave >> 1) * 64, wn = (wave & 1) * 64;
  const int l15 = lane & 15, kg = (lane >> 4) * 8;
  for (int k0 = 0; k0 < K; k0 += BK) {
    stage_tile(Ag + k0, As, K, tid);
    stage_tile(Bg + k0, Bs, K, tid);
    __syncthreads();                 // drains vmcnt -> LDS valid
    bf16x8 af[4], bfr[4];
#pragma unroll
    for (int i = 0; i < 4; ++i)
      af[i] = *(const bf16x8*)(As + (wm + i * 16 + l15) * BK + kg);
#pragma unroll
    for (int j = 0; j < 4; ++j)
      bfr[j] = *(const bf16x8*)(Bs + (wn + j * 16 + l15) * BK + kg);
#pragma unroll
    for (int i = 0; i < 4; ++i)
#pragma unroll
      for (int j = 0; j < 4; ++j)
        acc[i][j] = __builtin_amdgcn_mfma_f32_16x16x32_bf16(af[i], bfr[j], acc[i][j], 0, 0, 0);
    __syncthreads();                 // protect LDS for next k-step
  }
}

// ---------------- kernel 1: weight prep ----------------
// wqkv f32[3072][256] -> bf16 same layout.
// wout f32[256][1024] -> WoutR bf16[h][o][c] = wout[o][c*4+h]  (K-major per head)
__global__ void prep_w(const float* __restrict__ wqkv, const float* __restrict__ wout,
                       short* __restrict__ wbf, short* __restrict__ woR) {
  int i = blockIdx.x * 256 + threadIdx.x;
  if (i < 3072 * 256) wbf[i] = f2bf(wqkv[i]);
  if (i < 4 * 256 * 256) {
    int h = i >> 16, rem = i & 65535, o = rem >> 8, c = rem & 255;
    woR[i] = f2bf(wout[o * 1024 + c * 4 + h]);
  }
}

// ---------------- kernel 2: x[b][c][n] f32 -> xT[b][n][c] bf16 ----------------
__global__ void transpose_x(const float* __restrict__ x, short* __restrict__ xT) {
  __shared__ short tile[64][65];
  const int b  = blockIdx.y;
  const int c0 = (blockIdx.x >> 6) * 64;
  const int n0 = (blockIdx.x & 63) * 64;
  const int t  = threadIdx.x;
  const float* xp = x + (size_t)b * DIM * NTOK;
#pragma unroll
  for (int r = 0; r < 16; ++r) {
    int c = r * 4 + (t >> 6), n = t & 63;
    tile[c][n] = f2bf(xp[(size_t)(c0 + c) * NTOK + n0 + n]);
  }
  __syncthreads();
  short* xo = xT + (size_t)b * NTOK * DIM;
#pragma unroll
  for (int r = 0; r < 16; ++r) {
    int n = r * 4 + (t >> 6), c = t & 63;
    xo[(size_t)(n0 + n) * DIM + c0 + c] = tile[c][n];
  }
}

// ---------------- kernel 3: QKV projection ----------------
// qkv[o][n] = sum_c wbf[o][c] * xT[b][n][c];  o = which*1024 + h*256 + cc
// q: *1/16 -> qb[b][1024][4096]; k -> kb same; v -> vT[bh][n][c] (transposed store)
__global__ void __launch_bounds__(256, 2)
qkv_gemm(const short* __restrict__ Wbf, const short* __restrict__ xT,
         short* __restrict__ qb, short* __restrict__ kb, short* __restrict__ vT) {
  __shared__ __align__(16) short As[128 * BK], Bs[128 * BK];
  const int b = blockIdx.y;
  const int mtile = blockIdx.x / 32, ntile = blockIdx.x % 32;
  const int m0 = mtile * 128, n0 = ntile * 128;
  const short* Ag = Wbf + (size_t)m0 * 256;
  const short* Bg = xT + (size_t)b * NTOK * 256 + (size_t)n0 * 256;
  f32x4 acc[4][4] = {};
  gemm_core(Ag, Bg, 256, acc, As, Bs);

  const int lane = threadIdx.x & 63, wave = threadIdx.x >> 6;
  const int wm = (wave >> 1) * 64, wn = (wave & 1) * 64;
  const int which  = m0 >> 10;        // 0=q 1=k 2=v (uniform per block)
  const int olocal = m0 & 1023;
  if (which < 2) {
    short* dst = (which == 0) ? qb : kb;
    const float scl = (which == 0) ? 0.0625f : 1.0f;
    const size_t base = (size_t)b * 1024 * NTOK;
#pragma unroll
    for (int i = 0; i < 4; ++i)
#pragma unroll
      for (int j = 0; j < 4; ++j)
#pragma unroll
        for (int r = 0; r < 4; ++r) {
          int row = olocal + wm + i * 16 + ((lane >> 4) << 2) + r;
          int col = n0 + wn + j * 16 + (lane & 15);
          dst[base + (size_t)row * NTOK + col] = f2bf(acc[i][j][r] * scl);
        }
  } else {
#pragma unroll
    for (int i = 0; i < 4; ++i)
#pragma unroll
      for (int j = 0; j < 4; ++j) {
        int rbase = olocal + wm + i * 16 + ((lane >> 4) << 2);
        int col   = n0 + wn + j * 16 + (lane & 15);
        int h = rbase >> 8, c = rbase & 255;
        short4v o4;
#pragma unroll
        for (int r = 0; r < 4; ++r) o4[r] = f2bf(acc[i][j][r]);
        *(short4v*)(vT + ((size_t)(b * 4 + h) * NTOK + col) * 256 + c) = o4;
      }
  }
}

// ---------------- kernel 4: logits[bh][c][d] = sum_n q[c][n]*k[d][n] ----------------
__global__ void __launch_bounds__(256, 2)
logits_gemm(const short* __restrict__ qb, const short* __restrict__ kb,
            float* __restrict__ Lg) {
  __shared__ __align__(16) short As[128 * BK], Bs[128 * BK];
  const int bh = blockIdx.y;
  const int mtile = blockIdx.x >> 1, ntile = blockIdx.x & 1;
  const short* Ag = qb + ((size_t)bh * 256 + mtile * 128) * NTOK;
  const short* Bg = kb + ((size_t)bh * 256 + ntile * 128) * NTOK;
  f32x4 acc[4][4] = {};
  gemm_core(Ag, Bg, NTOK, acc, As, Bs);

  const int lane = threadIdx.x & 63, wave = threadIdx.x >> 6;
  const int wm = (wave >> 1) * 64, wn = (wave & 1) * 64;
  float* C = Lg + (size_t)bh * 65536;
#pragma unroll
  for (int i = 0; i < 4; ++i)
#pragma unroll
    for (int j = 0; j < 4; ++j)
#pragma unroll
      for (int r = 0; r < 4; ++r) {
        int row = mtile * 128 + wm + i * 16 + ((lane >> 4) << 2) + r;
        int col = ntile * 128 + wn + j * 16 + (lane & 15);
        C[(size_t)row * 256 + col] = acc[i][j][r];
      }
}

// ---------------- kernel 5: row softmax 256-wide, f32 -> bf16 ----------------
__global__ void softmax_k(const float* __restrict__ L, short* __restrict__ P) {
  const int row  = blockIdx.x * 4 + (threadIdx.x >> 6);   // 32*256 rows
  const int lane = threadIdx.x & 63;
  const float* lr = L + (size_t)row * 256;
  float v[4], m = -1e30f;
#pragma unroll
  for (int i = 0; i < 4; ++i) { v[i] = lr[lane + i * 64]; m = fmaxf(m, v[i]); }
  for (int off = 32; off; off >>= 1) m = fmaxf(m, __shfl_xor(m, off, 64));
  float s = 0.f;
#pragma unroll
  for (int i = 0; i < 4; ++i) { v[i] = __expf(v[i] - m); s += v[i]; }
  for (int off = 32; off; off >>= 1) s += __shfl_xor(s, off, 64);
  const float inv = 1.f / s;
  short* pr = P + (size_t)row * 256;
#pragma unroll
  for (int i = 0; i < 4; ++i) pr[lane + i * 64] = f2bf(v[i] * inv);
}

// ---------------- kernel 6: att[c][n] = sum_d P[c][d]*v[d][n]; store attT[bh][n][c] ----------------
__global__ void __launch_bounds__(256, 2)
pv_gemm(const short* __restrict__ P, const short* __restrict__ vT,
        short* __restrict__ attT) {
  __shared__ __align__(16) short As[128 * BK], Bs[128 * BK];
  const int bh = blockIdx.y;
  const int mtile = blockIdx.x >> 5, ntile = blockIdx.x & 31;
  const short* Ag = P + (size_t)bh * 65536 + (size_t)mtile * 128 * 256;
  const short* Bg = vT + (size_t)bh * NTOK * 256 + (size_t)(ntile * 128) * 256;
  f32x4 acc[4][4] = {};
  gemm_core(Ag, Bg, 256, acc, As, Bs);

  const int lane = threadIdx.x & 63, wave = threadIdx.x >> 6;
  const int wm = (wave >> 1) * 64, wn = (wave & 1) * 64;
#pragma unroll
  for (int i = 0; i < 4; ++i)
#pragma unroll
    for (int j = 0; j < 4; ++j) {
      int cb = mtile * 128 + wm + i * 16 + ((lane >> 4) << 2);
      int n  = ntile * 128 + wn + j * 16 + (lane & 15);
      short4v o4;
#pragma unroll
      for (int r = 0; r < 4; ++r) o4[r] = f2bf(acc[i][j][r]);
      *(short4v*)(attT + ((size_t)bh * NTOK + n) * 256 + cb) = o4;
    }
}

// ---------------- kernel 7: out[o][n] = sum_h sum_c WoutR[h][o][c]*attT[bh][n][c] + bias ----------------
__global__ void __launch_bounds__(256, 2)
out_gemm(const short* __restrict__ WoR, const short* __restrict__ attT,
         const float* __restrict__ bias, float* __restrict__ out) {
  __shared__ __align__(16) short As[128 * BK], Bs[128 * BK];
  const int b = blockIdx.y;
  const int mtile = blockIdx.x >> 5, ntile = blockIdx.x & 31;
  f32x4 acc[4][4] = {};
  for (int h = 0; h < 4; ++h) {
    const short* Ag = WoR + (size_t)h * 65536 + (size_t)mtile * 128 * 256;
    const short* Bg = attT + ((size_t)(b * 4 + h) * NTOK + ntile * 128) * 256;
    gemm_core(Ag, Bg, 256, acc, As, Bs);
  }
  const int lane = threadIdx.x & 63, wave = threadIdx.x >> 6;
  const int wm = (wave >> 1) * 64, wn = (wave & 1) * 64;
#pragma unroll
  for (int i = 0; i < 4; ++i)
#pragma unroll
    for (int j = 0; j < 4; ++j)
#pragma unroll
      for (int r = 0; r < 4; ++r) {
        int o = mtile * 128 + wm + i * 16 + ((lane >> 4) << 2) + r;
        int n = ntile * 128 + wn + j * 16 + (lane & 15);
        out[((size_t)b * 256 + o) * NTOK + n] = acc[i][j][r] + bias[o];
      }
}

extern "C" void kernel_launch(void* const* d_in, const int* in_sizes, int n_in,
                              void* d_out, int out_size, void* d_ws, size_t ws_size,
                              hipStream_t stream) {
  (void)in_sizes; (void)n_in; (void)out_size; (void)ws_size;
  const float* x     = (const float*)d_in[0];
  const float* wqkv  = (const float*)d_in[1];
  const float* wout  = (const float*)d_in[2];
  const float* bias  = (const float*)d_in[3];
  float* out = (float*)d_out;

  char* ws = (char*)d_ws;
  size_t off = 0;
  auto alloc = [&](size_t bytes) { char* p = ws + off; off += (bytes + 255) & ~(size_t)255; return p; };

  short* wbf = (short*)alloc((size_t)3072 * 256 * 2);        // 1.5 MB
  short* woR = (short*)alloc((size_t)4 * 256 * 256 * 2);     // 0.5 MB
  char*  xTr = alloc((size_t)BATCH * NTOK * 256 * 2);        // 16.8 MB (reused for logits+P)
  short* xT  = (short*)xTr;
  float* Lg  = (float*)xTr;                                  // 8.4 MB (after xT dead)
  short* P   = (short*)(xTr + (size_t)32 * 256 * 256 * 4);   // 4.2 MB
  short* qb  = (short*)alloc((size_t)BATCH * 1024 * NTOK * 2); // 67 MB (reused for attT)
  short* attT = qb;                                          // after logits consumed q
  short* kb  = (short*)alloc((size_t)BATCH * 1024 * NTOK * 2); // 67 MB
  short* vT  = (short*)alloc((size_t)BATCH * 1024 * NTOK * 2); // 67 MB
  // total ws: ~210 MB

  hipLaunchKernelGGL(prep_w,      dim3(3072),      dim3(256), 0, stream, wqkv, wout, wbf, woR);
  hipLaunchKernelGGL(transpose_x, dim3(256, 8),    dim3(256), 0, stream, x, xT);
  hipLaunchKernelGGL(qkv_gemm,    dim3(24 * 32, 8),dim3(256), 0, stream, wbf, xT, qb, kb, vT);
  hipLaunchKernelGGL(logits_gemm, dim3(4, 32),     dim3(256), 0, stream, qb, kb, Lg);
  hipLaunchKernelGGL(softmax_k,   dim3(2048),      dim3(256), 0, stream, Lg, P);
  hipLaunchKernelGGL(pv_gemm,     dim3(64, 32),    dim3(256), 0, stream, P, vT, attT);
  hipLaunchKernelGGL(out_gemm,    dim3(64, 8),     dim3(256), 0, stream, woR, attT, bias, out);
}